// Round 9
// baseline (456.639 us; speedup 1.0000x reference)
//
#include <hip/hip_runtime.h>
#include <math.h>

#define Bb 16
#define Tt 64
#define Nn 64
#define Ss 4
#define Dd 128
#define Hh 8
#define HD 16
#define BN 1024
#define G3 384   // 3*D
#define TT 8     // t-chunk for k_attn

// workspace layout (in floats)
#define OFF_WX   0                              // 4*384
#define OFF_BX   1536                           // 384
#define OFF_U1   1920                           // 128*8
#define OFF_U2   2944                           // 128*8
#define OFF_YS   4096                           // T*BN*D
#define OFF_KK   (OFF_YS + Tt*BN*Dd)            // [(b*T+t)*N + n]*D  (c = h*16+d)
#define OFF_QQ   (OFF_KK + Bb*Tt*Nn*Dd)
#define OFF_VW1  (OFF_QQ + Bb*Tt*Nn*Dd)         // [b][h][t][n]
#define OFF_VW2  (OFF_VW1 + Bb*Hh*Tt*Nn)
#define OFF_E    (OFF_VW2 + Bb*Hh*Tt*Nn)        // B*N*N
#define OFF_VV   (OFF_E + Bb*Nn*Nn)             // BN*D
#define WS_FLOATS (OFF_VV + BN*Dd)
// transient: f16x2-packed W_hh [64 pairs][384 cols] lives in KK region pre-k_kqv
#define OFF_WT   OFF_KK                         // 24576 u32 = 96 KB

typedef _Float16 half2_t __attribute__((ext_vector_type(2)));

__device__ __forceinline__ float fast_sigmoid(float v) {
  return 1.f / (1.f + __expf(-v));
}
__device__ __forceinline__ float fast_tanh(float v) {
  float e2 = __expf(2.f * v);
  return 1.f - 2.f / (e2 + 1.f);
}
__device__ __forceinline__ float fdot2(uint32_t a, uint32_t b, float c) {
  half2_t av = __builtin_bit_cast(half2_t, a);
  half2_t bv = __builtin_bit_cast(half2_t, b);
#if __has_builtin(__builtin_amdgcn_fdot2)
  return __builtin_amdgcn_fdot2(av, bv, c, false);
#else
  return c + (float)av.x * (float)bv.x + (float)av.y * (float)bv.y;
#endif
}
__device__ __forceinline__ uint32_t bcast_lane(uint32_t v, int l) {
  return (uint32_t)__builtin_amdgcn_readlane((int)v, l);
}

// ---------------- kernel 0: fold weights + pack W_hh to f16x2 ----------------
__global__ __launch_bounds__(384) void k_precompute(
    const float* __restrict__ W_se, const float* __restrict__ b_se,
    const float* __restrict__ W_ih, const float* __restrict__ b_ih,
    const float* __restrict__ W_hh,
    const float* __restrict__ W_vc, const float* __restrict__ W_att,
    float* __restrict__ ws) {
  const int tid = threadIdx.x;
  if (blockIdx.x > 0) {
    const int p = blockIdx.x - 1;     // pair index 0..63
    uint32_t* WT = (uint32_t*)(ws + OFF_WT);
    if (tid < G3) {
      float w0 = W_hh[(size_t)(2*p)*G3 + tid];
      float w1 = W_hh[(size_t)(2*p+1)*G3 + tid];
      half2_t hv; hv.x = (_Float16)w0; hv.y = (_Float16)w1;
      WT[(size_t)p*G3 + tid] = __builtin_bit_cast(uint32_t, hv);
    }
    return;
  }
  const int c = tid; // 0..383
  float* Wx = ws + OFF_WX; float* bx = ws + OFF_BX;
  float* u1 = ws + OFF_U1; float* u2 = ws + OFF_U2;
  float accb = b_ih[c];
  float a0 = 0.f, a1 = 0.f, a2 = 0.f, a3 = 0.f;
  for (int k = 0; k < Dd; ++k) {
    float w = W_ih[k*G3 + c];
    accb = fmaf(b_se[k], w, accb);
    a0 = fmaf(W_se[0*Dd + k], w, a0);
    a1 = fmaf(W_se[1*Dd + k], w, a1);
    a2 = fmaf(W_se[2*Dd + k], w, a2);
    a3 = fmaf(W_se[3*Dd + k], w, a3);
  }
  bx[c] = accb;
  Wx[0*G3 + c] = a0; Wx[1*G3 + c] = a1; Wx[2*G3 + c] = a2; Wx[3*G3 + c] = a3;
  for (int idx = c; idx < Dd*Hh; idx += 384) {
    int k = idx >> 3, h = idx & 7;
    float s1 = 0.f, s2 = 0.f;
    for (int d = 0; d < HD; ++d) {
      float v = W_vc[k*Dd + h*HD + d];
      s1 = fmaf(v, W_att[h*HD + d], s1);
      s2 = fmaf(v, W_att[Dd + h*HD + d], s2);
    }
    u1[k*Hh + h] = s1;
    u2[k*Hh + h] = s2;
  }
}

// ---------------- kernel 1: GRU — W in registers, h via v_readlane broadcast ----------------
// 4 rows/block, 256 blocks, 768 threads (12 waves, 3/SIMD). Thread = (col c,
// k-half kh, wave-aligned). Wreg[32] static-indexed (register-resident).
// h slice hp[r][lane] loaded 4xb32/step; pair operand via readlane (SGPR) into
// v_dot2. Inner loop has ZERO LDS instructions.
__global__ __launch_bounds__(768) void k_gru(
    const float* __restrict__ x, const float* __restrict__ W_init,
    const float* __restrict__ b_init,
    const float* __restrict__ b_hh, float* __restrict__ ws) {
  __shared__ uint32_t hp[4][Dd/2];                // f16x2 h, 1 KB
  __shared__ float ga[4][G3];                     // kh0 partial (+biases), 6 KB
  __shared__ float gb[4][G3];                     // kh1 partial, 6 KB
  __shared__ float gix[4][Dd];                    // gi for n-gate, 2 KB
  __shared__ float xt_l[Tt+1][4][Ss];             // 4.1 KB
  const int tid = threadIdx.x;
  const int kh = (tid >= G3) ? 1 : 0;             // wave-aligned (384 = 6 waves)
  const int c = tid - kh*G3;
  const int lane = tid & 63;
  const int blk = blockIdx.x;
  const int row0 = blk * 4;
  const int b = row0 >> 6;
  const int n0 = row0 & 63;
  float* ys = ws + OFF_YS;
  const float* Wx = ws + OFF_WX;
  const float* bxp = ws + OFF_BX;
  const uint32_t* WTg = (const uint32_t*)(ws + OFF_WT);
  const int pbase = kh * 32;

  // register-resident W: 32 u32 (f16x2 pairs) for this thread's column+half
  uint32_t Wreg[32];
  #pragma unroll
  for (int p = 0; p < 32; ++p)
    Wreg[p] = WTg[(size_t)(pbase + p)*G3 + c];

  for (int idx = tid; idx < (Tt+1)*4*Ss; idx += 768) {
    int t = idx >> 4, r = (idx >> 2) & 3, s = idx & 3;
    xt_l[t][r][s] = x[((size_t)(b*(Tt+1) + t)*Nn + (n0 + r))*Ss + s];
  }
  __syncthreads();

  // activation thread: tid<512 owns (row r, dim d); h kept f32 in register
  float hprev = 0.f;
  int r = 0, d = 0;
  if (tid < 4*Dd) {
    r = tid >> 7; d = tid & 127;
    float h0 = b_init[d];
    #pragma unroll
    for (int s = 0; s < Ss; ++s)
      h0 = fmaf(xt_l[0][r][s], W_init[s*Dd + d], h0);
    hprev = h0;
    ((_Float16*)hp)[r*Dd + d] = (_Float16)h0;
  }
  const float bhh = b_hh[c];
  const float wx0 = Wx[0*G3 + c], wx1 = Wx[1*G3 + c], wx2 = Wx[2*G3 + c], wx3 = Wx[3*G3 + c];
  const float bxv = bxp[c];
  __syncthreads();

  for (int t = 0; t < Tt; ++t) {
    // wave-local h slice (4 conflict-free b32 reads)
    uint32_t h0r = hp[0][lane];
    uint32_t h1r = hp[1][lane];
    uint32_t h2r = hp[2][lane];
    uint32_t h3r = hp[3][lane];
    float acc0 = 0.f, acc1 = 0.f, acc2 = 0.f, acc3 = 0.f;
    #pragma unroll
    for (int p = 0; p < 32; ++p) {
      const int ls = pbase + p;       // wave-uniform lane index
      uint32_t hb0 = bcast_lane(h0r, ls);
      uint32_t hb1 = bcast_lane(h1r, ls);
      uint32_t hb2 = bcast_lane(h2r, ls);
      uint32_t hb3 = bcast_lane(h3r, ls);
      acc0 = fdot2(hb0, Wreg[p], acc0);
      acc1 = fdot2(hb1, Wreg[p], acc1);
      acc2 = fdot2(hb2, Wreg[p], acc2);
      acc3 = fdot2(hb3, Wreg[p], acc3);
    }
    float accs[4] = {acc0, acc1, acc2, acc3};
    if (kh == 0) {
      float gi[4];
      #pragma unroll
      for (int rr = 0; rr < 4; ++rr) {
        float g = bxv;
        g = fmaf(xt_l[t][rr][0], wx0, g);
        g = fmaf(xt_l[t][rr][1], wx1, g);
        g = fmaf(xt_l[t][rr][2], wx2, g);
        g = fmaf(xt_l[t][rr][3], wx3, g);
        gi[rr] = g;
      }
      if (c < 2*Dd) {
        #pragma unroll
        for (int rr = 0; rr < 4; ++rr) ga[rr][c] = accs[rr] + gi[rr] + bhh;
      } else {
        #pragma unroll
        for (int rr = 0; rr < 4; ++rr) {
          ga[rr][c] = accs[rr] + bhh;     // hn partial (hidden bias)
          gix[rr][c - 2*Dd] = gi[rr];     // inn (input part incl. bx)
        }
      }
    } else {
      #pragma unroll
      for (int rr = 0; rr < 4; ++rr) gb[rr][c] = accs[rr];
    }
    __syncthreads();
    if (tid < 4*Dd) {
      float rg = fast_sigmoid(ga[r][d] + gb[r][d]);
      float zg = fast_sigmoid(ga[r][Dd + d] + gb[r][Dd + d]);
      float hn_h = ga[r][2*Dd + d] + gb[r][2*Dd + d];
      float ng = fast_tanh(fmaf(rg, hn_h, gix[r][d]));
      float hnew = fmaf(zg, hprev - ng, ng);   // (1-z)*n + z*h
      hprev = hnew;
      ((_Float16*)hp)[r*Dd + d] = (_Float16)hnew;
      ys[(size_t)(t*BN + row0 + r)*Dd + d] = hnew;
    }
    __syncthreads();
  }
}

// ---------------- kernel 2: k,q projections, 8x8 register-tile GEMM ----------------
// launch_bounds(256,3): ~168 VGPR cap so acc[8][8] stays in VGPRs.
__global__ __launch_bounds__(256, 3) void k_kqv(
    const float* __restrict__ W_kc, const float* __restrict__ W_qc,
    float* __restrict__ ws) {
  __shared__ __align__(16) float yslT[Dd][68];  // transposed, padded: 34.8 KB
  const int tid = threadIdx.x;
  const int blk = blockIdx.x;    // b*T + t
  const int b = blk >> 6;
  const int t = blk & 63;
  const float* ysrc = ws + OFF_YS + ((size_t)t*BN + b*64)*Dd;
  for (int idx = tid; idx < 64*Dd/4; idx += 256) {
    int r = idx >> 5, k4 = idx & 31;
    float4 v = *(const float4*)&ysrc[r*Dd + k4*4];
    yslT[k4*4+0][r] = v.x;
    yslT[k4*4+1][r] = v.y;
    yslT[k4*4+2][r] = v.z;
    yslT[k4*4+3][r] = v.w;
  }
  __syncthreads();

  const int rg = tid >> 5;          // 0..7  (row group)
  const int cg = tid & 31;          // 0..31 (col group)
  const int row0 = rg * 8;
  const float* Wm = (cg < 16) ? W_kc : W_qc;
  const int col0 = (cg & 15) * 8;
  const float* wp = Wm + col0;

  float acc[8][8];
  #pragma unroll
  for (int r = 0; r < 8; ++r)
    #pragma unroll
    for (int cc = 0; cc < 8; ++cc) acc[r][cc] = 0.f;

  float4 bv0 = *(const float4*)&wp[0];
  float4 bv1 = *(const float4*)&wp[4];
  for (int k = 0; k < Dd; ++k) {
    const int kn = (k + 1) & 127;
    float4 nb0 = *(const float4*)&wp[kn*Dd];
    float4 nb1 = *(const float4*)&wp[kn*Dd + 4];
    float4 a0 = *(const float4*)&yslT[k][row0];
    float4 a1 = *(const float4*)&yslT[k][row0 + 4];
    float ar[8] = {a0.x, a0.y, a0.z, a0.w, a1.x, a1.y, a1.z, a1.w};
    float br[8] = {bv0.x, bv0.y, bv0.z, bv0.w, bv1.x, bv1.y, bv1.z, bv1.w};
    #pragma unroll
    for (int r = 0; r < 8; ++r)
      #pragma unroll
      for (int cc = 0; cc < 8; ++cc)
        acc[r][cc] = fmaf(ar[r], br[cc], acc[r][cc]);
    bv0 = nb0; bv1 = nb1;
  }

  float* dst = ws + ((cg < 16) ? OFF_KK : OFF_QQ);
  const size_t base = (size_t)blk * Nn * Dd;
  #pragma unroll
  for (int r = 0; r < 8; ++r) {
    float4 o0 = {acc[r][0], acc[r][1], acc[r][2], acc[r][3]};
    float4 o1 = {acc[r][4], acc[r][5], acc[r][6], acc[r][7]};
    *(float4*)&dst[base + (size_t)(row0 + r)*Dd + col0] = o0;
    *(float4*)&dst[base + (size_t)(row0 + r)*Dd + col0 + 4] = o1;
  }

  const float* u1 = ws + OFF_U1;
  const float* u2 = ws + OFF_U2;
  for (int idx = tid; idx < 64*HD; idx += 256) {
    int r = idx >> 4, g = idx & 15, h2 = g >> 1, which = g & 1;
    const float* u = which ? u2 : u1;
    float s = 0.f;
    for (int k = 0; k < Dd; ++k) s = fmaf(yslT[k][r], u[k*Hh + h2], s);
    float* vw = ws + (which ? OFF_VW2 : OFF_VW1);
    vw[((size_t)(b*Hh + h2)*Tt + t)*Nn + r] = s;
  }
}

// ---------------- kernel 3: per-pair temporal online softmax, t-chunked LDS ----------------
__global__ __launch_bounds__(256) void k_attn(float* __restrict__ ws) {
  __shared__ __align__(16) float k_l[16][TT][HD];   // 8 KB
  __shared__ float q_l[TT][HD][Nn+1];               // 33.3 KB
  __shared__ float vw1_l[TT][16], vw2_l[TT][16];    // 1 KB
  const int tid = threadIdx.x;
  const int blk = blockIdx.x;         // (b*H+h)*4 + quarter
  const int quarter = blk & 3;
  const int bh = blk >> 2;
  const int b = bh >> 3;
  const int h = bh & 7;
  const int ch = h * HD;
  const int i0 = quarter * 16;
  const float* kk = ws + OFF_KK + (size_t)b*Tt*Nn*Dd;
  const float* qq = ws + OFF_QQ + (size_t)b*Tt*Nn*Dd;
  const float* vw1 = ws + OFF_VW1 + (size_t)bh*Tt*Nn;
  const float* vw2 = ws + OFF_VW2 + (size_t)bh*Tt*Nn;
  float* e = ws + OFF_E + (size_t)b*Nn*Nn;
  const int j = tid & 63, wq = tid >> 6;
  float m[4], Ssum[4], A1[4], A2[4];
  #pragma unroll
  for (int p = 0; p < 4; ++p) { m[p] = -1e30f; Ssum[p] = 0.f; A1[p] = 0.f; A2[p] = 0.f; }
  const float scale = 0.08838834764831845f; // 1/sqrt(128)

  for (int tc = 0; tc < Tt/TT; ++tc) {
    const int tbase = tc * TT;
    __syncthreads();
    #pragma unroll
    for (int s = 0; s < 2; ++s) {
      int fi = tid + s*256;
      int d4 = fi & 3, ttl = (fi >> 2) & 7, il = fi >> 5;
      float4 v = *(const float4*)&kk[((size_t)(tbase + ttl)*Nn + i0 + il)*Dd + ch + d4*4];
      *(float4*)&k_l[il][ttl][d4*4] = v;
    }
    #pragma unroll
    for (int s = 0; s < 8; ++s) {
      int fi = tid + s*256;
      int d4 = fi & 3, jg = (fi >> 2) & 63, ttl = fi >> 8;
      float4 v = *(const float4*)&qq[((size_t)(tbase + ttl)*Nn + jg)*Dd + ch + d4*4];
      q_l[ttl][d4*4+0][jg] = v.x;
      q_l[ttl][d4*4+1][jg] = v.y;
      q_l[ttl][d4*4+2][jg] = v.z;
      q_l[ttl][d4*4+3][jg] = v.w;
    }
    {
      int which = tid >> 7, ttl = (tid >> 4) & 7, ii = tid & 15;
      const float* src = which ? vw2 : vw1;
      float v = src[(size_t)(tbase + ttl)*Nn + i0 + ii];
      if (which) vw2_l[ttl][ii] = v; else vw1_l[ttl][ii] = v;
    }
    __syncthreads();

    for (int ttl = 0; ttl < TT; ++ttl) {
      float qr[16];
      #pragma unroll
      for (int dd = 0; dd < 16; ++dd) qr[dd] = q_l[ttl][dd][j];
      #pragma unroll
      for (int p = 0; p < 4; ++p) {
        const int il = wq + 4*p;
        float4 k0 = *(const float4*)&k_l[il][ttl][0];
        float4 k1 = *(const float4*)&k_l[il][ttl][4];
        float4 k2 = *(const float4*)&k_l[il][ttl][8];
        float4 k3 = *(const float4*)&k_l[il][ttl][12];
        float s = 0.f;
        s = fmaf(qr[0],  k0.x, s); s = fmaf(qr[1],  k0.y, s);
        s = fmaf(qr[2],  k0.z, s); s = fmaf(qr[3],  k0.w, s);
        s = fmaf(qr[4],  k1.x, s); s = fmaf(qr[5],  k1.y, s);
        s = fmaf(qr[6],  k1.z, s); s = fmaf(qr[7],  k1.w, s);
        s = fmaf(qr[8],  k2.x, s); s = fmaf(qr[9],  k2.y, s);
        s = fmaf(qr[10], k2.z, s); s = fmaf(qr[11], k2.w, s);
        s = fmaf(qr[12], k3.x, s); s = fmaf(qr[13], k3.y, s);
        s = fmaf(qr[14], k3.z, s); s = fmaf(qr[15], k3.w, s);
        s *= scale;
        float mn = fmaxf(m[p], s);
        float cc2 = __expf(m[p] - mn);
        float pp = __expf(s - mn);
        Ssum[p] = fmaf(Ssum[p], cc2, pp);
        A1[p] = fmaf(A1[p], cc2, pp * vw1_l[ttl][il]);
        A2[p] = fmaf(A2[p], cc2, pp * vw2_l[ttl][il]);
        m[p] = mn;
      }
    }
  }
  #pragma unroll
  for (int p = 0; p < 4; ++p) {
    const int i = i0 + wq + 4*p;
    float inv = 1.f / Ssum[p];
    atomicAdd(&e[i*Nn + j], A1[p] * inv);
    atomicAdd(&e[j*Nn + i], A2[p] * inv);
  }
}

// ---------------- kernel 4: decode GRU step + vv ----------------
__global__ __launch_bounds__(384) void k_decode(
    const float* __restrict__ x, const float* __restrict__ W_hh,
    const float* __restrict__ b_hh, const float* __restrict__ W_val,
    const float* __restrict__ b_val, float* __restrict__ ws) {
  __shared__ float h_lds[4][Dd];
  __shared__ float g_lds[4][4*Dd];
  __shared__ float xt[4][Ss];
  const int tid = threadIdx.x;
  const int blk = blockIdx.x;
  const int row0 = blk * 4;
  const int b = row0 >> 6;
  const int n0 = row0 & 63;
  const float* ys = ws + OFF_YS;
  const float* Wx = ws + OFF_WX;
  const float* bxp = ws + OFF_BX;
  if (tid < Dd) {
    for (int r = 0; r < 4; ++r)
      h_lds[r][tid] = ys[(size_t)((Tt-1)*BN + row0 + r)*Dd + tid];
  }
  if (tid >= 320 && tid < 336) {
    int q = tid - 320; int r = q >> 2, s = q & 3;
    xt[r][s] = x[((size_t)(b*(Tt+1) + Tt)*Nn + (n0 + r))*Ss + s];
  }
  const int c = tid;
  const float bhh = b_hh[c];
  const float wx0 = Wx[0*G3 + c], wx1 = Wx[1*G3 + c], wx2 = Wx[2*G3 + c], wx3 = Wx[3*G3 + c];
  const float bxv = bxp[c];
  __syncthreads();
  float acc[4] = {bhh, bhh, bhh, bhh};
  for (int k = 0; k < Dd; k += 4) {
    float w0 = W_hh[(k+0)*G3 + c];
    float w1 = W_hh[(k+1)*G3 + c];
    float w2 = W_hh[(k+2)*G3 + c];
    float w3 = W_hh[(k+3)*G3 + c];
    #pragma unroll
    for (int r = 0; r < 4; ++r) {
      float4 hv = *(const float4*)&h_lds[r][k];
      acc[r] = fmaf(hv.x, w0, acc[r]);
      acc[r] = fmaf(hv.y, w1, acc[r]);
      acc[r] = fmaf(hv.z, w2, acc[r]);
      acc[r] = fmaf(hv.w, w3, acc[r]);
    }
  }
  float gi[4];
  #pragma unroll
  for (int r = 0; r < 4; ++r) {
    float g = bxv;
    g = fmaf(xt[r][0], wx0, g);
    g = fmaf(xt[r][1], wx1, g);
    g = fmaf(xt[r][2], wx2, g);
    g = fmaf(xt[r][3], wx3, g);
    gi[r] = g;
  }
  if (c < 2*Dd) {
    #pragma unroll
    for (int r = 0; r < 4; ++r) g_lds[r][c] = acc[r] + gi[r];
  } else {
    #pragma unroll
    for (int r = 0; r < 4; ++r) { g_lds[r][c] = gi[r]; g_lds[r][c + Dd] = acc[r]; }
  }
  __syncthreads();
  if (tid < Dd) {
    const int d = tid;
    #pragma unroll
    for (int r = 0; r < 4; ++r) {
      float rg = fast_sigmoid(g_lds[r][d]);
      float zg = fast_sigmoid(g_lds[r][Dd + d]);
      float ng = fast_tanh(fmaf(rg, g_lds[r][3*Dd + d], g_lds[r][2*Dd + d]));
      float hn = fmaf(zg, h_lds[r][d] - ng, ng);
      h_lds[r][d] = hn;
    }
  }
  __syncthreads();
  if (tid < Dd) {
    const int c2 = tid;
    for (int r = 0; r < 4; ++r) {
      float a = b_val[c2];
      for (int k = 0; k < Dd; k += 4) {
        float4 hv = *(const float4*)&h_lds[r][k];
        a = fmaf(hv.x, W_val[(k+0)*Dd + c2], a);
        a = fmaf(hv.y, W_val[(k+1)*Dd + c2], a);
        a = fmaf(hv.z, W_val[(k+2)*Dd + c2], a);
        a = fmaf(hv.w, W_val[(k+3)*Dd + c2], a);
      }
      ws[OFF_VV + (size_t)(row0 + r)*Dd + c2] = a;
    }
  }
}

// ---------------- kernel 5: weight/p/dec/mu/sig ----------------
__global__ __launch_bounds__(256) void k_final(
    const float* __restrict__ W_dec, const float* __restrict__ b_dec,
    const float* __restrict__ W_mu, const float* __restrict__ b_mu,
    const float* __restrict__ W_sig, const float* __restrict__ b_sig,
    const float* __restrict__ b_att, float* __restrict__ ws,
    float* __restrict__ out) {
  __shared__ float vvl[64][Dd];  // 32KB
  __shared__ float wl[16][64];
  __shared__ float pl[16][Dd];
  __shared__ float ddl[16][Dd];
  const int tid = threadIdx.x;
  const int blk = blockIdx.x;
  const int b = blk >> 2, iq = blk & 3, i0 = iq*16;
  const float* vv = ws + OFF_VV + (size_t)b*64*Dd;
  const float* e = ws + OFF_E + (size_t)b*Nn*Nn;
  const float batt = b_att[0];
  for (int idx = tid; idx < 64*Dd; idx += 256) ((float*)vvl)[idx] = vv[idx];
  for (int idx = tid; idx < 16*64; idx += 256) {
    int il = idx >> 6, jj = idx & 63;
    int i = i0 + il;
    wl[il][jj] = (i == jj) ? 0.f : fast_tanh(e[i*Nn + jj] + batt + 0.5f);
  }
  __syncthreads();
  {
    const int d = tid & 127, ih = tid >> 7;
    #pragma unroll
    for (int kk2 = 0; kk2 < 8; ++kk2) {
      int il = ih*8 + kk2;
      float a = 0.f;
      for (int jj = 0; jj < 64; ++jj) a = fmaf(wl[il][jj], vvl[jj][d], a);
      pl[il][d] = a * (1.f/64.f);
    }
  }
  __syncthreads();
  {
    const int e2 = tid & 127, ih = tid >> 7;
    #pragma unroll
    for (int kk2 = 0; kk2 < 8; ++kk2) {
      int il = ih*8 + kk2;
      float a = b_dec[e2];
      for (int c2 = 0; c2 < Dd; ++c2) a = fmaf(vvl[i0 + il][c2], W_dec[c2*Dd + e2], a);
      for (int c2 = 0; c2 < Dd; ++c2) a = fmaf(pl[il][c2], W_dec[(Dd + c2)*Dd + e2], a);
      ddl[il][e2] = a;
    }
  }
  __syncthreads();
  if (tid < 128) {
    const int il = tid >> 3, g = tid & 7, which = g >> 2, s = g & 3;
    const float* W = which ? W_sig : W_mu;
    float a = which ? b_sig[s] : b_mu[s];
    for (int k = 0; k < Dd; ++k) a = fmaf(ddl[il][k], W[k*Ss + s], a);
    if (which) a = 1.f/(1.f + __expf(-a)) + 1e-6f;
    out[(size_t)which*(Bb*Nn*Ss) + (size_t)(b*64 + i0 + il)*Ss + s] = a;
  }
}

extern "C" void kernel_launch(void* const* d_in, const int* in_sizes, int n_in,
                              void* d_out, int out_size, void* d_ws, size_t ws_size,
                              hipStream_t stream) {
  const float* x     = (const float*)d_in[0];
  const float* W_se  = (const float*)d_in[1];
  const float* b_se  = (const float*)d_in[2];
  const float* W_init= (const float*)d_in[3];
  const float* b_init= (const float*)d_in[4];
  const float* W_ih  = (const float*)d_in[5];
  const float* W_hh  = (const float*)d_in[6];
  const float* b_ih  = (const float*)d_in[7];
  const float* b_hh  = (const float*)d_in[8];
  const float* W_kc  = (const float*)d_in[9];
  const float* W_qc  = (const float*)d_in[10];
  const float* W_vc  = (const float*)d_in[11];
  const float* W_att = (const float*)d_in[12];
  const float* b_att = (const float*)d_in[13];
  const float* W_val = (const float*)d_in[14];
  const float* b_val = (const float*)d_in[15];
  const float* W_dec = (const float*)d_in[16];
  const float* b_dec = (const float*)d_in[17];
  const float* W_mu  = (const float*)d_in[18];
  const float* b_mu  = (const float*)d_in[19];
  const float* W_sig = (const float*)d_in[20];
  const float* b_sig = (const float*)d_in[21];
  float* ws = (float*)d_ws;
  float* out = (float*)d_out;

  if (ws_size < (size_t)WS_FLOATS * sizeof(float)) return;

  hipMemsetAsync(ws + OFF_E, 0, (size_t)Bb*Nn*Nn*sizeof(float), stream);
  k_precompute<<<65, 384, 0, stream>>>(W_se, b_se, W_ih, b_ih, W_hh, W_vc, W_att, ws);
  k_gru<<<BN/4, 768, 0, stream>>>(x, W_init, b_init, b_hh, ws);
  k_kqv<<<Bb*Tt, 256, 0, stream>>>(W_kc, W_qc, ws);
  k_attn<<<Bb*Hh*4, 256, 0, stream>>>(ws);
  k_decode<<<BN/4, 384, 0, stream>>>(x, W_hh, b_hh, W_val, b_val, ws);
  k_final<<<Bb*4, 256, 0, stream>>>(W_dec, b_dec, W_mu, b_mu, W_sig, b_sig, b_att, ws, out);
}

// Round 10
// 324.211 us; speedup vs baseline: 1.4085x; 1.4085x over previous
//
#include <hip/hip_runtime.h>
#include <math.h>

#define Bb 16
#define Tt 64
#define Nn 64
#define Ss 4
#define Dd 128
#define Hh 8
#define HD 16
#define BN 1024
#define G3 384   // 3*D
#define TT 8     // t-chunk for k_attn

// workspace layout (in floats)
#define OFF_WX   0                              // 4*384
#define OFF_BX   1536                           // 384
#define OFF_U1   1920                           // 128*8
#define OFF_U2   2944                           // 128*8
#define OFF_YS   4096                           // T*BN*D
#define OFF_KK   (OFF_YS + Tt*BN*Dd)            // [(b*T+t)*N + n]*D  (c = h*16+d)
#define OFF_QQ   (OFF_KK + Bb*Tt*Nn*Dd)
#define OFF_VW1  (OFF_QQ + Bb*Tt*Nn*Dd)         // [b][h][t][n]
#define OFF_VW2  (OFF_VW1 + Bb*Hh*Tt*Nn)
#define OFF_E    (OFF_VW2 + Bb*Hh*Tt*Nn)        // B*N*N
#define OFF_VV   (OFF_E + Bb*Nn*Nn)             // BN*D
#define WS_FLOATS (OFF_VV + BN*Dd)
// transient: MFMA-fragment-packed f16 W_hh lives in KK region pre-k_kqv
// layout: frag16[((nt*4+ks)*64+lane)*8+j] = W_hh[ks*32+(lane>>4)*8+j][nt*16+(lane&15)]
#define OFF_WT   OFF_KK                         // 49152 f16 = 96 KB

typedef _Float16 half2_t __attribute__((ext_vector_type(2)));
typedef _Float16 f16x8 __attribute__((ext_vector_type(8)));
typedef float f32x4 __attribute__((ext_vector_type(4)));

__device__ __forceinline__ float fast_sigmoid(float v) {
  return 1.f / (1.f + __expf(-v));
}
__device__ __forceinline__ float fast_tanh(float v) {
  float e2 = __expf(2.f * v);
  return 1.f - 2.f / (e2 + 1.f);
}

// ---------------- kernel 0: fold weights + pack W_hh into MFMA B-fragments ----------------
__global__ __launch_bounds__(384) void k_precompute(
    const float* __restrict__ W_se, const float* __restrict__ b_se,
    const float* __restrict__ W_ih, const float* __restrict__ b_ih,
    const float* __restrict__ W_hh,
    const float* __restrict__ W_vc, const float* __restrict__ W_att,
    float* __restrict__ ws) {
  const int tid = threadIdx.x;
  if (blockIdx.x > 0) {
    // B-fragment packing for N-tile nt = blockIdx.x-1 (24 tiles of 16 cols)
    const int nt = blockIdx.x - 1;
    _Float16* WF = (_Float16*)(ws + OFF_WT);
    for (int idx = tid; idx < 4*64*8; idx += 384) {
      int ks = idx >> 9, l = (idx >> 3) & 63, j = idx & 7;
      int k = ks*32 + (l >> 4)*8 + j;
      int c = nt*16 + (l & 15);
      WF[(size_t)((nt*4 + ks)*64 + l)*8 + j] = (_Float16)W_hh[(size_t)k*G3 + c];
    }
    return;
  }
  const int c = tid; // 0..383
  float* Wx = ws + OFF_WX; float* bx = ws + OFF_BX;
  float* u1 = ws + OFF_U1; float* u2 = ws + OFF_U2;
  float accb = b_ih[c];
  float a0 = 0.f, a1 = 0.f, a2 = 0.f, a3 = 0.f;
  for (int k = 0; k < Dd; ++k) {
    float w = W_ih[k*G3 + c];
    accb = fmaf(b_se[k], w, accb);
    a0 = fmaf(W_se[0*Dd + k], w, a0);
    a1 = fmaf(W_se[1*Dd + k], w, a1);
    a2 = fmaf(W_se[2*Dd + k], w, a2);
    a3 = fmaf(W_se[3*Dd + k], w, a3);
  }
  bx[c] = accb;
  Wx[0*G3 + c] = a0; Wx[1*G3 + c] = a1; Wx[2*G3 + c] = a2; Wx[3*G3 + c] = a3;
  for (int idx = c; idx < Dd*Hh; idx += 384) {
    int k = idx >> 3, h = idx & 7;
    float s1 = 0.f, s2 = 0.f;
    for (int d = 0; d < HD; ++d) {
      float v = W_vc[k*Dd + h*HD + d];
      s1 = fmaf(v, W_att[h*HD + d], s1);
      s2 = fmaf(v, W_att[Dd + h*HD + d], s2);
    }
    u1[k*Hh + h] = s1;
    u2[k*Hh + h] = s2;
  }
}

// ---------------- kernel 1: GRU via MFMA (f16), W fragments register-resident ----------------
// 4 rows/block (M padded to 16 in-fragment), 256 blocks, 512 threads = 8 waves.
// Wave w owns N-tiles w*3..w*3+2 (24 x 16 cols = 384). gh = h@W_hh via
// mfma_f32_16x16x32_f16, b_hh rides in the C operand. Activation: 1 thread
// per (row,dim), x-path (12 fmaf) in registers. h kept f32/thread + f16 LDS.
__global__ __launch_bounds__(512, 2) void k_gru(
    const float* __restrict__ x, const float* __restrict__ W_init,
    const float* __restrict__ b_init,
    const float* __restrict__ b_hh, float* __restrict__ ws) {
  __shared__ __align__(16) _Float16 h_l[4][Dd + 8];  // padded: A-reads hit 16 banks
  __shared__ float gg[4][G3];                        // gate h-parts, 6 KB
  __shared__ float xt_l[Tt+1][4][Ss];                // 4.2 KB
  const int tid = threadIdx.x;
  const int wave = tid >> 6;
  const int lane = tid & 63;
  const int l15 = lane & 15;
  const int lk = lane >> 4;
  const int blk = blockIdx.x;
  const int row0 = blk * 4;
  const int b = row0 >> 6;
  const int n0 = row0 & 63;
  float* ys = ws + OFF_YS;
  const float* Wx = ws + OFF_WX;
  const float* bxp = ws + OFF_BX;

  // register-resident W fragments: 3 N-tiles x 4 k-steps x 8 f16
  const f16x8* WF = (const f16x8*)(ws + OFF_WT);
  f16x8 wf[3][4];
  #pragma unroll
  for (int i = 0; i < 3; ++i)
    #pragma unroll
    for (int ks = 0; ks < 4; ++ks)
      wf[i][ks] = WF[(size_t)((wave*3 + i)*4 + ks)*64 + lane];
  // bias (b_hh) per owned N-tile column
  float br[3];
  #pragma unroll
  for (int i = 0; i < 3; ++i) br[i] = b_hh[(wave*3 + i)*16 + l15];

  // activation-thread constants: thread owns (row, d)
  const int row = tid >> 7, d = tid & 127;
  float wxr[3][4], bx3[3];
  #pragma unroll
  for (int g = 0; g < 3; ++g) {
    bx3[g] = bxp[g*Dd + d];
    #pragma unroll
    for (int s = 0; s < 4; ++s) wxr[g][s] = Wx[s*G3 + g*Dd + d];
  }

  // stage x frames for our 4 rows
  for (int idx = tid; idx < (Tt+1)*4*Ss; idx += 512) {
    int t = idx >> 4, r = (idx >> 2) & 3, s = idx & 3;
    xt_l[t][r][s] = x[((size_t)(b*(Tt+1) + t)*Nn + (n0 + r))*Ss + s];
  }
  __syncthreads();

  // h0 = x[:,0] @ W_init + b_init
  float hprev;
  {
    float h0 = b_init[d];
    #pragma unroll
    for (int s = 0; s < Ss; ++s)
      h0 = fmaf(xt_l[0][row][s], W_init[s*Dd + d], h0);
    hprev = h0;
    h_l[row][d] = (_Float16)h0;
  }
  __syncthreads();

  for (int t = 0; t < Tt; ++t) {
    // A fragments: lane reads h row (l15&3) [rows 4-15 duplicate 0-3: harmless],
    // k-slice ks*32 + lk*8 (8 f16 = 16B)
    f16x8 af[4];
    #pragma unroll
    for (int ks = 0; ks < 4; ++ks)
      af[ks] = *(const f16x8*)&h_l[l15 & 3][ks*32 + lk*8];
    #pragma unroll
    for (int i = 0; i < 3; ++i) {
      f32x4 acc = {br[i], br[i], br[i], br[i]};
      #pragma unroll
      for (int ks = 0; ks < 4; ++ks)
        acc = __builtin_amdgcn_mfma_f32_16x16x32_f16(af[ks], wf[i][ks], acc, 0, 0, 0);
      if (lane < 16) {
        const int col = (wave*3 + i)*16 + l15;
        gg[0][col] = acc[0];
        gg[1][col] = acc[1];
        gg[2][col] = acc[2];
        gg[3][col] = acc[3];
      }
    }
    __syncthreads();
    // activation: thread (row,d)
    {
      float gi_r = bx3[0], gi_z = bx3[1], gi_n = bx3[2];
      #pragma unroll
      for (int s = 0; s < 4; ++s) {
        float xv = xt_l[t][row][s];
        gi_r = fmaf(xv, wxr[0][s], gi_r);
        gi_z = fmaf(xv, wxr[1][s], gi_z);
        gi_n = fmaf(xv, wxr[2][s], gi_n);
      }
      float rg = fast_sigmoid(gi_r + gg[row][d]);
      float zg = fast_sigmoid(gi_z + gg[row][Dd + d]);
      float ng = fast_tanh(fmaf(rg, gg[row][2*Dd + d], gi_n));
      float hnew = fmaf(zg, hprev - ng, ng);   // (1-z)*n + z*h
      hprev = hnew;
      h_l[row][d] = (_Float16)hnew;
      ys[(size_t)(t*BN + row0 + row)*Dd + d] = hnew;
    }
    __syncthreads();
  }
}

// ---------------- kernel 2: k,q projections, 8x8 register-tile GEMM ----------------
// launch_bounds(256,3): ~168 VGPR cap so acc[8][8] stays in VGPRs.
__global__ __launch_bounds__(256, 3) void k_kqv(
    const float* __restrict__ W_kc, const float* __restrict__ W_qc,
    float* __restrict__ ws) {
  __shared__ __align__(16) float yslT[Dd][68];  // transposed, padded: 34.8 KB
  const int tid = threadIdx.x;
  const int blk = blockIdx.x;    // b*T + t
  const int b = blk >> 6;
  const int t = blk & 63;
  const float* ysrc = ws + OFF_YS + ((size_t)t*BN + b*64)*Dd;
  for (int idx = tid; idx < 64*Dd/4; idx += 256) {
    int r = idx >> 5, k4 = idx & 31;
    float4 v = *(const float4*)&ysrc[r*Dd + k4*4];
    yslT[k4*4+0][r] = v.x;
    yslT[k4*4+1][r] = v.y;
    yslT[k4*4+2][r] = v.z;
    yslT[k4*4+3][r] = v.w;
  }
  __syncthreads();

  const int rg = tid >> 5;          // 0..7  (row group)
  const int cg = tid & 31;          // 0..31 (col group)
  const int row0 = rg * 8;
  const float* Wm = (cg < 16) ? W_kc : W_qc;
  const int col0 = (cg & 15) * 8;
  const float* wp = Wm + col0;

  float acc[8][8];
  #pragma unroll
  for (int r = 0; r < 8; ++r)
    #pragma unroll
    for (int cc = 0; cc < 8; ++cc) acc[r][cc] = 0.f;

  float4 bv0 = *(const float4*)&wp[0];
  float4 bv1 = *(const float4*)&wp[4];
  for (int k = 0; k < Dd; ++k) {
    const int kn = (k + 1) & 127;
    float4 nb0 = *(const float4*)&wp[kn*Dd];
    float4 nb1 = *(const float4*)&wp[kn*Dd + 4];
    float4 a0 = *(const float4*)&yslT[k][row0];
    float4 a1 = *(const float4*)&yslT[k][row0 + 4];
    float ar[8] = {a0.x, a0.y, a0.z, a0.w, a1.x, a1.y, a1.z, a1.w};
    float br[8] = {bv0.x, bv0.y, bv0.z, bv0.w, bv1.x, bv1.y, bv1.z, bv1.w};
    #pragma unroll
    for (int r = 0; r < 8; ++r)
      #pragma unroll
      for (int cc = 0; cc < 8; ++cc)
        acc[r][cc] = fmaf(ar[r], br[cc], acc[r][cc]);
    bv0 = nb0; bv1 = nb1;
  }

  float* dst = ws + ((cg < 16) ? OFF_KK : OFF_QQ);
  const size_t base = (size_t)blk * Nn * Dd;
  #pragma unroll
  for (int r = 0; r < 8; ++r) {
    float4 o0 = {acc[r][0], acc[r][1], acc[r][2], acc[r][3]};
    float4 o1 = {acc[r][4], acc[r][5], acc[r][6], acc[r][7]};
    *(float4*)&dst[base + (size_t)(row0 + r)*Dd + col0] = o0;
    *(float4*)&dst[base + (size_t)(row0 + r)*Dd + col0 + 4] = o1;
  }

  const float* u1 = ws + OFF_U1;
  const float* u2 = ws + OFF_U2;
  for (int idx = tid; idx < 64*HD; idx += 256) {
    int r = idx >> 4, g = idx & 15, h2 = g >> 1, which = g & 1;
    const float* u = which ? u2 : u1;
    float s = 0.f;
    for (int k = 0; k < Dd; ++k) s = fmaf(yslT[k][r], u[k*Hh + h2], s);
    float* vw = ws + (which ? OFF_VW2 : OFF_VW1);
    vw[((size_t)(b*Hh + h2)*Tt + t)*Nn + r] = s;
  }
}

// ---------------- kernel 3: per-pair temporal online softmax, t-chunked LDS ----------------
__global__ __launch_bounds__(256) void k_attn(float* __restrict__ ws) {
  __shared__ __align__(16) float k_l[16][TT][HD];   // 8 KB
  __shared__ float q_l[TT][HD][Nn+1];               // 33.3 KB
  __shared__ float vw1_l[TT][16], vw2_l[TT][16];    // 1 KB
  const int tid = threadIdx.x;
  const int blk = blockIdx.x;         // (b*H+h)*4 + quarter
  const int quarter = blk & 3;
  const int bh = blk >> 2;
  const int b = bh >> 3;
  const int h = bh & 7;
  const int ch = h * HD;
  const int i0 = quarter * 16;
  const float* kk = ws + OFF_KK + (size_t)b*Tt*Nn*Dd;
  const float* qq = ws + OFF_QQ + (size_t)b*Tt*Nn*Dd;
  const float* vw1 = ws + OFF_VW1 + (size_t)bh*Tt*Nn;
  const float* vw2 = ws + OFF_VW2 + (size_t)bh*Tt*Nn;
  float* e = ws + OFF_E + (size_t)b*Nn*Nn;
  const int j = tid & 63, wq = tid >> 6;
  float m[4], Ssum[4], A1[4], A2[4];
  #pragma unroll
  for (int p = 0; p < 4; ++p) { m[p] = -1e30f; Ssum[p] = 0.f; A1[p] = 0.f; A2[p] = 0.f; }
  const float scale = 0.08838834764831845f; // 1/sqrt(128)

  for (int tc = 0; tc < Tt/TT; ++tc) {
    const int tbase = tc * TT;
    __syncthreads();
    #pragma unroll
    for (int s = 0; s < 2; ++s) {
      int fi = tid + s*256;
      int d4 = fi & 3, ttl = (fi >> 2) & 7, il = fi >> 5;
      float4 v = *(const float4*)&kk[((size_t)(tbase + ttl)*Nn + i0 + il)*Dd + ch + d4*4];
      *(float4*)&k_l[il][ttl][d4*4] = v;
    }
    #pragma unroll
    for (int s = 0; s < 8; ++s) {
      int fi = tid + s*256;
      int d4 = fi & 3, jg = (fi >> 2) & 63, ttl = fi >> 8;
      float4 v = *(const float4*)&qq[((size_t)(tbase + ttl)*Nn + jg)*Dd + ch + d4*4];
      q_l[ttl][d4*4+0][jg] = v.x;
      q_l[ttl][d4*4+1][jg] = v.y;
      q_l[ttl][d4*4+2][jg] = v.z;
      q_l[ttl][d4*4+3][jg] = v.w;
    }
    {
      int which = tid >> 7, ttl = (tid >> 4) & 7, ii = tid & 15;
      const float* src = which ? vw2 : vw1;
      float v = src[(size_t)(tbase + ttl)*Nn + i0 + ii];
      if (which) vw2_l[ttl][ii] = v; else vw1_l[ttl][ii] = v;
    }
    __syncthreads();

    for (int ttl = 0; ttl < TT; ++ttl) {
      float qr[16];
      #pragma unroll
      for (int dd = 0; dd < 16; ++dd) qr[dd] = q_l[ttl][dd][j];
      #pragma unroll
      for (int p = 0; p < 4; ++p) {
        const int il = wq + 4*p;
        float4 k0 = *(const float4*)&k_l[il][ttl][0];
        float4 k1 = *(const float4*)&k_l[il][ttl][4];
        float4 k2 = *(const float4*)&k_l[il][ttl][8];
        float4 k3 = *(const float4*)&k_l[il][ttl][12];
        float s = 0.f;
        s = fmaf(qr[0],  k0.x, s); s = fmaf(qr[1],  k0.y, s);
        s = fmaf(qr[2],  k0.z, s); s = fmaf(qr[3],  k0.w, s);
        s = fmaf(qr[4],  k1.x, s); s = fmaf(qr[5],  k1.y, s);
        s = fmaf(qr[6],  k1.z, s); s = fmaf(qr[7],  k1.w, s);
        s = fmaf(qr[8],  k2.x, s); s = fmaf(qr[9],  k2.y, s);
        s = fmaf(qr[10], k2.z, s); s = fmaf(qr[11], k2.w, s);
        s = fmaf(qr[12], k3.x, s); s = fmaf(qr[13], k3.y, s);
        s = fmaf(qr[14], k3.z, s); s = fmaf(qr[15], k3.w, s);
        s *= scale;
        float mn = fmaxf(m[p], s);
        float cc2 = __expf(m[p] - mn);
        float pp = __expf(s - mn);
        Ssum[p] = fmaf(Ssum[p], cc2, pp);
        A1[p] = fmaf(A1[p], cc2, pp * vw1_l[ttl][il]);
        A2[p] = fmaf(A2[p], cc2, pp * vw2_l[ttl][il]);
        m[p] = mn;
      }
    }
  }
  #pragma unroll
  for (int p = 0; p < 4; ++p) {
    const int i = i0 + wq + 4*p;
    float inv = 1.f / Ssum[p];
    atomicAdd(&e[i*Nn + j], A1[p] * inv);
    atomicAdd(&e[j*Nn + i], A2[p] * inv);
  }
}

// ---------------- kernel 4: decode GRU step + vv ----------------
__global__ __launch_bounds__(384) void k_decode(
    const float* __restrict__ x, const float* __restrict__ W_hh,
    const float* __restrict__ b_hh, const float* __restrict__ W_val,
    const float* __restrict__ b_val, float* __restrict__ ws) {
  __shared__ float h_lds[4][Dd];
  __shared__ float g_lds[4][4*Dd];
  __shared__ float xt[4][Ss];
  const int tid = threadIdx.x;
  const int blk = blockIdx.x;
  const int row0 = blk * 4;
  const int b = row0 >> 6;
  const int n0 = row0 & 63;
  const float* ys = ws + OFF_YS;
  const float* Wx = ws + OFF_WX;
  const float* bxp = ws + OFF_BX;
  if (tid < Dd) {
    for (int r = 0; r < 4; ++r)
      h_lds[r][tid] = ys[(size_t)((Tt-1)*BN + row0 + r)*Dd + tid];
  }
  if (tid >= 320 && tid < 336) {
    int q = tid - 320; int r = q >> 2, s = q & 3;
    xt[r][s] = x[((size_t)(b*(Tt+1) + Tt)*Nn + (n0 + r))*Ss + s];
  }
  const int c = tid;
  const float bhh = b_hh[c];
  const float wx0 = Wx[0*G3 + c], wx1 = Wx[1*G3 + c], wx2 = Wx[2*G3 + c], wx3 = Wx[3*G3 + c];
  const float bxv = bxp[c];
  __syncthreads();
  float acc[4] = {bhh, bhh, bhh, bhh};
  for (int k = 0; k < Dd; k += 4) {
    float w0 = W_hh[(k+0)*G3 + c];
    float w1 = W_hh[(k+1)*G3 + c];
    float w2 = W_hh[(k+2)*G3 + c];
    float w3 = W_hh[(k+3)*G3 + c];
    #pragma unroll
    for (int r = 0; r < 4; ++r) {
      float4 hv = *(const float4*)&h_lds[r][k];
      acc[r] = fmaf(hv.x, w0, acc[r]);
      acc[r] = fmaf(hv.y, w1, acc[r]);
      acc[r] = fmaf(hv.z, w2, acc[r]);
      acc[r] = fmaf(hv.w, w3, acc[r]);
    }
  }
  float gi[4];
  #pragma unroll
  for (int r = 0; r < 4; ++r) {
    float g = bxv;
    g = fmaf(xt[r][0], wx0, g);
    g = fmaf(xt[r][1], wx1, g);
    g = fmaf(xt[r][2], wx2, g);
    g = fmaf(xt[r][3], wx3, g);
    gi[r] = g;
  }
  if (c < 2*Dd) {
    #pragma unroll
    for (int r = 0; r < 4; ++r) g_lds[r][c] = acc[r] + gi[r];
  } else {
    #pragma unroll
    for (int r = 0; r < 4; ++r) { g_lds[r][c] = gi[r]; g_lds[r][c + Dd] = acc[r]; }
  }
  __syncthreads();
  if (tid < Dd) {
    const int d = tid;
    #pragma unroll
    for (int r = 0; r < 4; ++r) {
      float rg = fast_sigmoid(g_lds[r][d]);
      float zg = fast_sigmoid(g_lds[r][Dd + d]);
      float ng = fast_tanh(fmaf(rg, g_lds[r][3*Dd + d], g_lds[r][2*Dd + d]));
      float hn = fmaf(zg, h_lds[r][d] - ng, ng);
      h_lds[r][d] = hn;
    }
  }
  __syncthreads();
  if (tid < Dd) {
    const int c2 = tid;
    for (int r = 0; r < 4; ++r) {
      float a = b_val[c2];
      for (int k = 0; k < Dd; k += 4) {
        float4 hv = *(const float4*)&h_lds[r][k];
        a = fmaf(hv.x, W_val[(k+0)*Dd + c2], a);
        a = fmaf(hv.y, W_val[(k+1)*Dd + c2], a);
        a = fmaf(hv.z, W_val[(k+2)*Dd + c2], a);
        a = fmaf(hv.w, W_val[(k+3)*Dd + c2], a);
      }
      ws[OFF_VV + (size_t)(row0 + r)*Dd + c2] = a;
    }
  }
}

// ---------------- kernel 5: weight/p/dec/mu/sig ----------------
__global__ __launch_bounds__(256) void k_final(
    const float* __restrict__ W_dec, const float* __restrict__ b_dec,
    const float* __restrict__ W_mu, const float* __restrict__ b_mu,
    const float* __restrict__ W_sig, const float* __restrict__ b_sig,
    const float* __restrict__ b_att, float* __restrict__ ws,
    float* __restrict__ out) {
  __shared__ float vvl[64][Dd];  // 32KB
  __shared__ float wl[16][64];
  __shared__ float pl[16][Dd];
  __shared__ float ddl[16][Dd];
  const int tid = threadIdx.x;
  const int blk = blockIdx.x;
  const int b = blk >> 2, iq = blk & 3, i0 = iq*16;
  const float* vv = ws + OFF_VV + (size_t)b*64*Dd;
  const float* e = ws + OFF_E + (size_t)b*Nn*Nn;
  const float batt = b_att[0];
  for (int idx = tid; idx < 64*Dd; idx += 256) ((float*)vvl)[idx] = vv[idx];
  for (int idx = tid; idx < 16*64; idx += 256) {
    int il = idx >> 6, jj = idx & 63;
    int i = i0 + il;
    wl[il][jj] = (i == jj) ? 0.f : fast_tanh(e[i*Nn + jj] + batt + 0.5f);
  }
  __syncthreads();
  {
    const int d = tid & 127, ih = tid >> 7;
    #pragma unroll
    for (int kk2 = 0; kk2 < 8; ++kk2) {
      int il = ih*8 + kk2;
      float a = 0.f;
      for (int jj = 0; jj < 64; ++jj) a = fmaf(wl[il][jj], vvl[jj][d], a);
      pl[il][d] = a * (1.f/64.f);
    }
  }
  __syncthreads();
  {
    const int e2 = tid & 127, ih = tid >> 7;
    #pragma unroll
    for (int kk2 = 0; kk2 < 8; ++kk2) {
      int il = ih*8 + kk2;
      float a = b_dec[e2];
      for (int c2 = 0; c2 < Dd; ++c2) a = fmaf(vvl[i0 + il][c2], W_dec[c2*Dd + e2], a);
      for (int c2 = 0; c2 < Dd; ++c2) a = fmaf(pl[il][c2], W_dec[(Dd + c2)*Dd + e2], a);
      ddl[il][e2] = a;
    }
  }
  __syncthreads();
  if (tid < 128) {
    const int il = tid >> 3, g = tid & 7, which = g >> 2, s = g & 3;
    const float* W = which ? W_sig : W_mu;
    float a = which ? b_sig[s] : b_mu[s];
    for (int k = 0; k < Dd; ++k) a = fmaf(ddl[il][k], W[k*Ss + s], a);
    if (which) a = 1.f/(1.f + __expf(-a)) + 1e-6f;
    out[(size_t)which*(Bb*Nn*Ss) + (size_t)(b*64 + i0 + il)*Ss + s] = a;
  }
}

extern "C" void kernel_launch(void* const* d_in, const int* in_sizes, int n_in,
                              void* d_out, int out_size, void* d_ws, size_t ws_size,
                              hipStream_t stream) {
  const float* x     = (const float*)d_in[0];
  const float* W_se  = (const float*)d_in[1];
  const float* b_se  = (const float*)d_in[2];
  const float* W_init= (const float*)d_in[3];
  const float* b_init= (const float*)d_in[4];
  const float* W_ih  = (const float*)d_in[5];
  const float* W_hh  = (const float*)d_in[6];
  const float* b_ih  = (const float*)d_in[7];
  const float* b_hh  = (const float*)d_in[8];
  const float* W_kc  = (const float*)d_in[9];
  const float* W_qc  = (const float*)d_in[10];
  const float* W_vc  = (const float*)d_in[11];
  const float* W_att = (const float*)d_in[12];
  const float* b_att = (const float*)d_in[13];
  const float* W_val = (const float*)d_in[14];
  const float* b_val = (const float*)d_in[15];
  const float* W_dec = (const float*)d_in[16];
  const float* b_dec = (const float*)d_in[17];
  const float* W_mu  = (const float*)d_in[18];
  const float* b_mu  = (const float*)d_in[19];
  const float* W_sig = (const float*)d_in[20];
  const float* b_sig = (const float*)d_in[21];
  float* ws = (float*)d_ws;
  float* out = (float*)d_out;

  if (ws_size < (size_t)WS_FLOATS * sizeof(float)) return;

  hipMemsetAsync(ws + OFF_E, 0, (size_t)Bb*Nn*Nn*sizeof(float), stream);
  k_precompute<<<25, 384, 0, stream>>>(W_se, b_se, W_ih, b_ih, W_hh, W_vc, W_att, ws);
  k_gru<<<BN/4, 512, 0, stream>>>(x, W_init, b_init, b_hh, ws);
  k_kqv<<<Bb*Tt, 256, 0, stream>>>(W_kc, W_qc, ws);
  k_attn<<<Bb*Hh*4, 256, 0, stream>>>(ws);
  k_decode<<<BN/4, 384, 0, stream>>>(x, W_hh, b_hh, W_val, b_val, ws);
  k_final<<<Bb*4, 256, 0, stream>>>(W_dec, b_dec, W_mu, b_mu, W_sig, b_sig, b_att, ws, out);
}

// Round 11
// 222.802 us; speedup vs baseline: 2.0495x; 1.4551x over previous
//
#include <hip/hip_runtime.h>
#include <math.h>

#define Bb 16
#define Tt 64
#define Nn 64
#define Ss 4
#define Dd 128
#define Hh 8
#define HD 16
#define BN 1024
#define G3 384   // 3*D
#define TT 8     // t-chunk for k_attn

// workspace layout (in floats)
#define OFF_WX   0                              // 4*384
#define OFF_BX   1536                           // 384
#define OFF_U1   1920                           // 128*8
#define OFF_U2   2944                           // 128*8
#define OFF_YS   4096                           // T*BN*D
#define OFF_KK   (OFF_YS + Tt*BN*Dd)            // [(b*T+t)*N + n]*D  (c = h*16+d)
#define OFF_QQ   (OFF_KK + Bb*Tt*Nn*Dd)
#define OFF_VW1  (OFF_QQ + Bb*Tt*Nn*Dd)         // [b][h][t][n]
#define OFF_VW2  (OFF_VW1 + Bb*Hh*Tt*Nn)
#define OFF_E    (OFF_VW2 + Bb*Hh*Tt*Nn)        // B*N*N
#define OFF_VV   (OFF_E + Bb*Nn*Nn)             // BN*D
// MFMA-fragment-packed f16 [W_kc|W_qc|u] (17 N-tiles): 17*4*64*8 f16 = 17408 floats
#define OFF_WKQ  (OFF_VV + BN*Dd)
#define WS_FLOATS (OFF_WKQ + 17408)
// transient: MFMA-fragment-packed f16 W_hh lives in KK region pre-k_kqv
#define OFF_WT   OFF_KK                         // 49152 f16 = 96 KB

typedef _Float16 f16x8 __attribute__((ext_vector_type(8)));
typedef float f32x4 __attribute__((ext_vector_type(4)));

__device__ __forceinline__ float fast_sigmoid(float v) {
  return 1.f / (1.f + __expf(-v));
}
__device__ __forceinline__ float fast_tanh(float v) {
  float e2 = __expf(2.f * v);
  return 1.f - 2.f / (e2 + 1.f);
}

// ---------------- kernel 0: fold weights + pack W_hh / W_kq / u fragments ----------------
// block 0: fold Wx/bx (+u1/u2); blocks 1..24: W_hh B-frags; 25..41: W_kq+u B-frags.
__global__ __launch_bounds__(384) void k_precompute(
    const float* __restrict__ W_se, const float* __restrict__ b_se,
    const float* __restrict__ W_ih, const float* __restrict__ b_ih,
    const float* __restrict__ W_hh,
    const float* __restrict__ W_kc, const float* __restrict__ W_qc,
    const float* __restrict__ W_vc, const float* __restrict__ W_att,
    float* __restrict__ ws) {
  const int tid = threadIdx.x;
  if (blockIdx.x >= 25) {
    // W_kq + u fragment packing, N-tile nt = blockIdx.x-25 (0..16)
    const int nt = blockIdx.x - 25;
    _Float16* WF = (_Float16*)(ws + OFF_WKQ);
    for (int idx = tid; idx < 4*64*8; idx += 384) {
      int ks = idx >> 9, l = (idx >> 3) & 63, j = idx & 7;
      int k = ks*32 + (l >> 4)*8 + j;
      int c16 = l & 15;
      float v;
      if (nt < 16) {
        int cg = nt*16 + c16;
        v = (cg < Dd) ? W_kc[(size_t)k*Dd + cg] : W_qc[(size_t)k*Dd + cg - Dd];
      } else {
        int h = c16 >> 1, which = c16 & 1;
        float s = 0.f;
        for (int d = 0; d < HD; ++d)
          s = fmaf(W_vc[(size_t)k*Dd + h*HD + d], W_att[which*Dd + h*HD + d], s);
        v = s;
      }
      WF[(size_t)((nt*4 + ks)*64 + l)*8 + j] = (_Float16)v;
    }
    return;
  }
  if (blockIdx.x > 0) {
    // W_hh B-fragment packing, N-tile nt = blockIdx.x-1 (0..23)
    const int nt = blockIdx.x - 1;
    _Float16* WF = (_Float16*)(ws + OFF_WT);
    for (int idx = tid; idx < 4*64*8; idx += 384) {
      int ks = idx >> 9, l = (idx >> 3) & 63, j = idx & 7;
      int k = ks*32 + (l >> 4)*8 + j;
      int c = nt*16 + (l & 15);
      WF[(size_t)((nt*4 + ks)*64 + l)*8 + j] = (_Float16)W_hh[(size_t)k*G3 + c];
    }
    return;
  }
  const int c = tid; // 0..383
  float* Wx = ws + OFF_WX; float* bx = ws + OFF_BX;
  float accb = b_ih[c];
  float a0 = 0.f, a1 = 0.f, a2 = 0.f, a3 = 0.f;
  for (int k = 0; k < Dd; ++k) {
    float w = W_ih[k*G3 + c];
    accb = fmaf(b_se[k], w, accb);
    a0 = fmaf(W_se[0*Dd + k], w, a0);
    a1 = fmaf(W_se[1*Dd + k], w, a1);
    a2 = fmaf(W_se[2*Dd + k], w, a2);
    a3 = fmaf(W_se[3*Dd + k], w, a3);
  }
  bx[c] = accb;
  Wx[0*G3 + c] = a0; Wx[1*G3 + c] = a1; Wx[2*G3 + c] = a2; Wx[3*G3 + c] = a3;
}

// ---------------- kernel 1: GRU via MFMA (f16), W fragments register-resident ----------------
__global__ __launch_bounds__(512, 2) void k_gru(
    const float* __restrict__ x, const float* __restrict__ W_init,
    const float* __restrict__ b_init,
    const float* __restrict__ b_hh, float* __restrict__ ws) {
  __shared__ __align__(16) _Float16 h_l[4][Dd + 8];
  __shared__ float gg[4][G3];
  __shared__ float xt_l[Tt+1][4][Ss];
  const int tid = threadIdx.x;
  const int wave = tid >> 6;
  const int lane = tid & 63;
  const int l15 = lane & 15;
  const int lk = lane >> 4;
  const int blk = blockIdx.x;
  const int row0 = blk * 4;
  const int b = row0 >> 6;
  const int n0 = row0 & 63;
  float* ys = ws + OFF_YS;
  const float* Wx = ws + OFF_WX;
  const float* bxp = ws + OFF_BX;

  const f16x8* WF = (const f16x8*)(ws + OFF_WT);
  f16x8 wf[3][4];
  #pragma unroll
  for (int i = 0; i < 3; ++i)
    #pragma unroll
    for (int ks = 0; ks < 4; ++ks)
      wf[i][ks] = WF[(size_t)((wave*3 + i)*4 + ks)*64 + lane];
  float br[3];
  #pragma unroll
  for (int i = 0; i < 3; ++i) br[i] = b_hh[(wave*3 + i)*16 + l15];

  const int row = tid >> 7, d = tid & 127;
  float wxr[3][4], bx3[3];
  #pragma unroll
  for (int g = 0; g < 3; ++g) {
    bx3[g] = bxp[g*Dd + d];
    #pragma unroll
    for (int s = 0; s < 4; ++s) wxr[g][s] = Wx[s*G3 + g*Dd + d];
  }

  for (int idx = tid; idx < (Tt+1)*4*Ss; idx += 512) {
    int t = idx >> 4, r = (idx >> 2) & 3, s = idx & 3;
    xt_l[t][r][s] = x[((size_t)(b*(Tt+1) + t)*Nn + (n0 + r))*Ss + s];
  }
  __syncthreads();

  float hprev;
  {
    float h0 = b_init[d];
    #pragma unroll
    for (int s = 0; s < Ss; ++s)
      h0 = fmaf(xt_l[0][row][s], W_init[s*Dd + d], h0);
    hprev = h0;
    h_l[row][d] = (_Float16)h0;
  }
  __syncthreads();

  for (int t = 0; t < Tt; ++t) {
    f16x8 af[4];
    #pragma unroll
    for (int ks = 0; ks < 4; ++ks)
      af[ks] = *(const f16x8*)&h_l[l15 & 3][ks*32 + lk*8];
    #pragma unroll
    for (int i = 0; i < 3; ++i) {
      f32x4 acc = {br[i], br[i], br[i], br[i]};
      #pragma unroll
      for (int ks = 0; ks < 4; ++ks)
        acc = __builtin_amdgcn_mfma_f32_16x16x32_f16(af[ks], wf[i][ks], acc, 0, 0, 0);
      if (lane < 16) {
        const int col = (wave*3 + i)*16 + l15;
        gg[0][col] = acc[0];
        gg[1][col] = acc[1];
        gg[2][col] = acc[2];
        gg[3][col] = acc[3];
      }
    }
    __syncthreads();
    {
      float gi_r = bx3[0], gi_z = bx3[1], gi_n = bx3[2];
      #pragma unroll
      for (int s = 0; s < 4; ++s) {
        float xv = xt_l[t][row][s];
        gi_r = fmaf(xv, wxr[0][s], gi_r);
        gi_z = fmaf(xv, wxr[1][s], gi_z);
        gi_n = fmaf(xv, wxr[2][s], gi_n);
      }
      float rg = fast_sigmoid(gi_r + gg[row][d]);
      float zg = fast_sigmoid(gi_z + gg[row][Dd + d]);
      float ng = fast_tanh(fmaf(rg, gg[row][2*Dd + d], gi_n));
      float hnew = fmaf(zg, hprev - ng, ng);
      hprev = hnew;
      h_l[row][d] = (_Float16)hnew;
      ys[(size_t)(t*BN + row0 + row)*Dd + d] = hnew;
    }
    __syncthreads();
  }
}

// ---------------- kernel 2: k,q,vw via MFMA (f16) ----------------
// block = (b,t): [64x128] ys @ [128x272] (K||Q||u). 4 waves; wave w owns
// N-tiles w*4..w*4+3; wave 3 also the u-tile (vw1/vw2). B frags register-
// resident; ys staged f16 in LDS (pad->2-way banks, free).
__global__ __launch_bounds__(256, 2) void k_kqv(float* __restrict__ ws) {
  __shared__ __align__(16) _Float16 ysl[64][136];  // 17.4 KB
  const int tid = threadIdx.x;
  const int blk = blockIdx.x;    // b*T + t
  const int b = blk >> 6, t = blk & 63;
  const int wave = tid >> 6, lane = tid & 63;
  const int l15 = lane & 15, lk = lane >> 4;

  const f16x8* WKQ = (const f16x8*)(ws + OFF_WKQ);
  f16x8 bf0[4], bf1[4], bf2[4], bf3[4], bu[4];
  #pragma unroll
  for (int ks = 0; ks < 4; ++ks) {
    bf0[ks] = WKQ[(size_t)((wave*4 + 0)*4 + ks)*64 + lane];
    bf1[ks] = WKQ[(size_t)((wave*4 + 1)*4 + ks)*64 + lane];
    bf2[ks] = WKQ[(size_t)((wave*4 + 2)*4 + ks)*64 + lane];
    bf3[ks] = WKQ[(size_t)((wave*4 + 3)*4 + ks)*64 + lane];
    bu[ks]  = WKQ[(size_t)(16*4 + ks)*64 + lane];
  }

  const float* ysrc = ws + OFF_YS + ((size_t)t*BN + b*64)*Dd;
  for (int idx = tid; idx < 64*16; idx += 256) {
    int r = idx >> 4, k8 = (idx & 15) * 8;
    float4 v0 = *(const float4*)&ysrc[r*Dd + k8];
    float4 v1 = *(const float4*)&ysrc[r*Dd + k8 + 4];
    f16x8 hv;
    hv[0] = (_Float16)v0.x; hv[1] = (_Float16)v0.y;
    hv[2] = (_Float16)v0.z; hv[3] = (_Float16)v0.w;
    hv[4] = (_Float16)v1.x; hv[5] = (_Float16)v1.y;
    hv[6] = (_Float16)v1.z; hv[7] = (_Float16)v1.w;
    *(f16x8*)&ysl[r][k8] = hv;
  }
  __syncthreads();

  float* kkd = ws + OFF_KK + (size_t)blk*Nn*Dd;
  float* qqd = ws + OFF_QQ + (size_t)blk*Nn*Dd;

  #pragma unroll
  for (int mt = 0; mt < 4; ++mt) {
    f16x8 af[4];
    #pragma unroll
    for (int ks = 0; ks < 4; ++ks)
      af[ks] = *(const f16x8*)&ysl[mt*16 + l15][ks*32 + lk*8];
    f32x4 a0 = {0.f,0.f,0.f,0.f}, a1 = a0, a2 = a0, a3 = a0;
    #pragma unroll
    for (int ks = 0; ks < 4; ++ks) {
      a0 = __builtin_amdgcn_mfma_f32_16x16x32_f16(af[ks], bf0[ks], a0, 0, 0, 0);
      a1 = __builtin_amdgcn_mfma_f32_16x16x32_f16(af[ks], bf1[ks], a1, 0, 0, 0);
      a2 = __builtin_amdgcn_mfma_f32_16x16x32_f16(af[ks], bf2[ks], a2, 0, 0, 0);
      a3 = __builtin_amdgcn_mfma_f32_16x16x32_f16(af[ks], bf3[ks], a3, 0, 0, 0);
    }
    const int rowb = mt*16 + lk*4;
    #pragma unroll
    for (int nti = 0; nti < 4; ++nti) {
      f32x4 av = (nti == 0) ? a0 : (nti == 1) ? a1 : (nti == 2) ? a2 : a3;
      const int gc = wave*64 + nti*16 + l15;
      float* dst = (gc < Dd) ? kkd : qqd;
      const int col = gc & 127;
      #pragma unroll
      for (int rg2 = 0; rg2 < 4; ++rg2)
        dst[(size_t)(rowb + rg2)*Dd + col] = av[rg2];
    }
    if (wave == 3) {
      f32x4 au = {0.f,0.f,0.f,0.f};
      #pragma unroll
      for (int ks = 0; ks < 4; ++ks)
        au = __builtin_amdgcn_mfma_f32_16x16x32_f16(af[ks], bu[ks], au, 0, 0, 0);
      const int h = l15 >> 1, which = l15 & 1;
      float* vw = ws + (which ? OFF_VW2 : OFF_VW1) + ((size_t)(b*Hh + h)*Tt + t)*Nn;
      #pragma unroll
      for (int rg2 = 0; rg2 < 4; ++rg2)
        vw[rowb + rg2] = au[rg2];
    }
  }
}

// ---------------- kernel 3: per-pair temporal online softmax, t-chunked LDS ----------------
__global__ __launch_bounds__(256) void k_attn(float* __restrict__ ws) {
  __shared__ __align__(16) float k_l[16][TT][HD];   // 8 KB
  __shared__ float q_l[TT][HD][Nn+1];               // 33.3 KB
  __shared__ float vw1_l[TT][16], vw2_l[TT][16];    // 1 KB
  const int tid = threadIdx.x;
  const int blk = blockIdx.x;         // (b*H+h)*4 + quarter
  const int quarter = blk & 3;
  const int bh = blk >> 2;
  const int b = bh >> 3;
  const int h = bh & 7;
  const int ch = h * HD;
  const int i0 = quarter * 16;
  const float* kk = ws + OFF_KK + (size_t)b*Tt*Nn*Dd;
  const float* qq = ws + OFF_QQ + (size_t)b*Tt*Nn*Dd;
  const float* vw1 = ws + OFF_VW1 + (size_t)bh*Tt*Nn;
  const float* vw2 = ws + OFF_VW2 + (size_t)bh*Tt*Nn;
  float* e = ws + OFF_E + (size_t)b*Nn*Nn;
  const int j = tid & 63, wq = tid >> 6;
  float m[4], Ssum[4], A1[4], A2[4];
  #pragma unroll
  for (int p = 0; p < 4; ++p) { m[p] = -1e30f; Ssum[p] = 0.f; A1[p] = 0.f; A2[p] = 0.f; }
  const float scale = 0.08838834764831845f; // 1/sqrt(128)

  for (int tc = 0; tc < Tt/TT; ++tc) {
    const int tbase = tc * TT;
    __syncthreads();
    #pragma unroll
    for (int s = 0; s < 2; ++s) {
      int fi = tid + s*256;
      int d4 = fi & 3, ttl = (fi >> 2) & 7, il = fi >> 5;
      float4 v = *(const float4*)&kk[((size_t)(tbase + ttl)*Nn + i0 + il)*Dd + ch + d4*4];
      *(float4*)&k_l[il][ttl][d4*4] = v;
    }
    #pragma unroll
    for (int s = 0; s < 8; ++s) {
      int fi = tid + s*256;
      int d4 = fi & 3, jg = (fi >> 2) & 63, ttl = fi >> 8;
      float4 v = *(const float4*)&qq[((size_t)(tbase + ttl)*Nn + jg)*Dd + ch + d4*4];
      q_l[ttl][d4*4+0][jg] = v.x;
      q_l[ttl][d4*4+1][jg] = v.y;
      q_l[ttl][d4*4+2][jg] = v.z;
      q_l[ttl][d4*4+3][jg] = v.w;
    }
    {
      int which = tid >> 7, ttl = (tid >> 4) & 7, ii = tid & 15;
      const float* src = which ? vw2 : vw1;
      float v = src[(size_t)(tbase + ttl)*Nn + i0 + ii];
      if (which) vw2_l[ttl][ii] = v; else vw1_l[ttl][ii] = v;
    }
    __syncthreads();

    for (int ttl = 0; ttl < TT; ++ttl) {
      float qr[16];
      #pragma unroll
      for (int dd = 0; dd < 16; ++dd) qr[dd] = q_l[ttl][dd][j];
      #pragma unroll
      for (int p = 0; p < 4; ++p) {
        const int il = wq + 4*p;
        float4 k0 = *(const float4*)&k_l[il][ttl][0];
        float4 k1 = *(const float4*)&k_l[il][ttl][4];
        float4 k2 = *(const float4*)&k_l[il][ttl][8];
        float4 k3 = *(const float4*)&k_l[il][ttl][12];
        float s = 0.f;
        s = fmaf(qr[0],  k0.x, s); s = fmaf(qr[1],  k0.y, s);
        s = fmaf(qr[2],  k0.z, s); s = fmaf(qr[3],  k0.w, s);
        s = fmaf(qr[4],  k1.x, s); s = fmaf(qr[5],  k1.y, s);
        s = fmaf(qr[6],  k1.z, s); s = fmaf(qr[7],  k1.w, s);
        s = fmaf(qr[8],  k2.x, s); s = fmaf(qr[9],  k2.y, s);
        s = fmaf(qr[10], k2.z, s); s = fmaf(qr[11], k2.w, s);
        s = fmaf(qr[12], k3.x, s); s = fmaf(qr[13], k3.y, s);
        s = fmaf(qr[14], k3.z, s); s = fmaf(qr[15], k3.w, s);
        s *= scale;
        float mn = fmaxf(m[p], s);
        float cc2 = __expf(m[p] - mn);
        float pp = __expf(s - mn);
        Ssum[p] = fmaf(Ssum[p], cc2, pp);
        A1[p] = fmaf(A1[p], cc2, pp * vw1_l[ttl][il]);
        A2[p] = fmaf(A2[p], cc2, pp * vw2_l[ttl][il]);
        m[p] = mn;
      }
    }
  }
  #pragma unroll
  for (int p = 0; p < 4; ++p) {
    const int i = i0 + wq + 4*p;
    float inv = 1.f / Ssum[p];
    atomicAdd(&e[i*Nn + j], A1[p] * inv);
    atomicAdd(&e[j*Nn + i], A2[p] * inv);
  }
}

// ---------------- kernel 4: decode GRU step + vv ----------------
__global__ __launch_bounds__(384) void k_decode(
    const float* __restrict__ x, const float* __restrict__ W_hh,
    const float* __restrict__ b_hh, const float* __restrict__ W_val,
    const float* __restrict__ b_val, float* __restrict__ ws) {
  __shared__ float h_lds[4][Dd];
  __shared__ float g_lds[4][4*Dd];
  __shared__ float xt[4][Ss];
  const int tid = threadIdx.x;
  const int blk = blockIdx.x;
  const int row0 = blk * 4;
  const int b = row0 >> 6;
  const int n0 = row0 & 63;
  const float* ys = ws + OFF_YS;
  const float* Wx = ws + OFF_WX;
  const float* bxp = ws + OFF_BX;
  if (tid < Dd) {
    for (int r = 0; r < 4; ++r)
      h_lds[r][tid] = ys[(size_t)((Tt-1)*BN + row0 + r)*Dd + tid];
  }
  if (tid >= 320 && tid < 336) {
    int q = tid - 320; int r = q >> 2, s = q & 3;
    xt[r][s] = x[((size_t)(b*(Tt+1) + Tt)*Nn + (n0 + r))*Ss + s];
  }
  const int c = tid;
  const float bhh = b_hh[c];
  const float wx0 = Wx[0*G3 + c], wx1 = Wx[1*G3 + c], wx2 = Wx[2*G3 + c], wx3 = Wx[3*G3 + c];
  const float bxv = bxp[c];
  __syncthreads();
  float acc[4] = {bhh, bhh, bhh, bhh};
  for (int k = 0; k < Dd; k += 4) {
    float w0 = W_hh[(k+0)*G3 + c];
    float w1 = W_hh[(k+1)*G3 + c];
    float w2 = W_hh[(k+2)*G3 + c];
    float w3 = W_hh[(k+3)*G3 + c];
    #pragma unroll
    for (int r = 0; r < 4; ++r) {
      float4 hv = *(const float4*)&h_lds[r][k];
      acc[r] = fmaf(hv.x, w0, acc[r]);
      acc[r] = fmaf(hv.y, w1, acc[r]);
      acc[r] = fmaf(hv.z, w2, acc[r]);
      acc[r] = fmaf(hv.w, w3, acc[r]);
    }
  }
  float gi[4];
  #pragma unroll
  for (int r = 0; r < 4; ++r) {
    float g = bxv;
    g = fmaf(xt[r][0], wx0, g);
    g = fmaf(xt[r][1], wx1, g);
    g = fmaf(xt[r][2], wx2, g);
    g = fmaf(xt[r][3], wx3, g);
    gi[r] = g;
  }
  if (c < 2*Dd) {
    #pragma unroll
    for (int r = 0; r < 4; ++r) g_lds[r][c] = acc[r] + gi[r];
  } else {
    #pragma unroll
    for (int r = 0; r < 4; ++r) { g_lds[r][c] = gi[r]; g_lds[r][c + Dd] = acc[r]; }
  }
  __syncthreads();
  if (tid < Dd) {
    const int d = tid;
    #pragma unroll
    for (int r = 0; r < 4; ++r) {
      float rg = fast_sigmoid(g_lds[r][d]);
      float zg = fast_sigmoid(g_lds[r][Dd + d]);
      float ng = fast_tanh(fmaf(rg, g_lds[r][3*Dd + d], g_lds[r][2*Dd + d]));
      float hn = fmaf(zg, h_lds[r][d] - ng, ng);
      h_lds[r][d] = hn;
    }
  }
  __syncthreads();
  if (tid < Dd) {
    const int c2 = tid;
    for (int r = 0; r < 4; ++r) {
      float a = b_val[c2];
      for (int k = 0; k < Dd; k += 4) {
        float4 hv = *(const float4*)&h_lds[r][k];
        a = fmaf(hv.x, W_val[(k+0)*Dd + c2], a);
        a = fmaf(hv.y, W_val[(k+1)*Dd + c2], a);
        a = fmaf(hv.z, W_val[(k+2)*Dd + c2], a);
        a = fmaf(hv.w, W_val[(k+3)*Dd + c2], a);
      }
      ws[OFF_VV + (size_t)(row0 + r)*Dd + c2] = a;
    }
  }
}

// ---------------- kernel 5: weight/p/dec/mu/sig ----------------
__global__ __launch_bounds__(256) void k_final(
    const float* __restrict__ W_dec, const float* __restrict__ b_dec,
    const float* __restrict__ W_mu, const float* __restrict__ b_mu,
    const float* __restrict__ W_sig, const float* __restrict__ b_sig,
    const float* __restrict__ b_att, float* __restrict__ ws,
    float* __restrict__ out) {
  __shared__ float vvl[64][Dd];  // 32KB
  __shared__ float wl[16][64];
  __shared__ float pl[16][Dd];
  __shared__ float ddl[16][Dd];
  const int tid = threadIdx.x;
  const int blk = blockIdx.x;
  const int b = blk >> 2, iq = blk & 3, i0 = iq*16;
  const float* vv = ws + OFF_VV + (size_t)b*64*Dd;
  const float* e = ws + OFF_E + (size_t)b*Nn*Nn;
  const float batt = b_att[0];
  for (int idx = tid; idx < 64*Dd; idx += 256) ((float*)vvl)[idx] = vv[idx];
  for (int idx = tid; idx < 16*64; idx += 256) {
    int il = idx >> 6, jj = idx & 63;
    int i = i0 + il;
    wl[il][jj] = (i == jj) ? 0.f : fast_tanh(e[i*Nn + jj] + batt + 0.5f);
  }
  __syncthreads();
  {
    const int d = tid & 127, ih = tid >> 7;
    #pragma unroll
    for (int kk2 = 0; kk2 < 8; ++kk2) {
      int il = ih*8 + kk2;
      float a = 0.f;
      for (int jj = 0; jj < 64; ++jj) a = fmaf(wl[il][jj], vvl[jj][d], a);
      pl[il][d] = a * (1.f/64.f);
    }
  }
  __syncthreads();
  {
    const int e2 = tid & 127, ih = tid >> 7;
    #pragma unroll
    for (int kk2 = 0; kk2 < 8; ++kk2) {
      int il = ih*8 + kk2;
      float a = b_dec[e2];
      for (int c2 = 0; c2 < Dd; ++c2) a = fmaf(vvl[i0 + il][c2], W_dec[c2*Dd + e2], a);
      for (int c2 = 0; c2 < Dd; ++c2) a = fmaf(pl[il][c2], W_dec[(Dd + c2)*Dd + e2], a);
      ddl[il][e2] = a;
    }
  }
  __syncthreads();
  if (tid < 128) {
    const int il = tid >> 3, g = tid & 7, which = g >> 2, s = g & 3;
    const float* W = which ? W_sig : W_mu;
    float a = which ? b_sig[s] : b_mu[s];
    for (int k = 0; k < Dd; ++k) a = fmaf(ddl[il][k], W[k*Ss + s], a);
    if (which) a = 1.f/(1.f + __expf(-a)) + 1e-6f;
    out[(size_t)which*(Bb*Nn*Ss) + (size_t)(b*64 + i0 + il)*Ss + s] = a;
  }
}

extern "C" void kernel_launch(void* const* d_in, const int* in_sizes, int n_in,
                              void* d_out, int out_size, void* d_ws, size_t ws_size,
                              hipStream_t stream) {
  const float* x     = (const float*)d_in[0];
  const float* W_se  = (const float*)d_in[1];
  const float* b_se  = (const float*)d_in[2];
  const float* W_init= (const float*)d_in[3];
  const float* b_init= (const float*)d_in[4];
  const float* W_ih  = (const float*)d_in[5];
  const float* W_hh  = (const float*)d_in[6];
  const float* b_ih  = (const float*)d_in[7];
  const float* b_hh  = (const float*)d_in[8];
  const float* W_kc  = (const float*)d_in[9];
  const float* W_qc  = (const float*)d_in[10];
  const float* W_vc  = (const float*)d_in[11];
  const float* W_att = (const float*)d_in[12];
  const float* b_att = (const float*)d_in[13];
  const float* W_val = (const float*)d_in[14];
  const float* b_val = (const float*)d_in[15];
  const float* W_dec = (const float*)d_in[16];
  const float* b_dec = (const float*)d_in[17];
  const float* W_mu  = (const float*)d_in[18];
  const float* b_mu  = (const float*)d_in[19];
  const float* W_sig = (const float*)d_in[20];
  const float* b_sig = (const float*)d_in[21];
  float* ws = (float*)d_ws;
  float* out = (float*)d_out;

  if (ws_size < (size_t)WS_FLOATS * sizeof(float)) return;

  hipMemsetAsync(ws + OFF_E, 0, (size_t)Bb*Nn*Nn*sizeof(float), stream);
  k_precompute<<<42, 384, 0, stream>>>(W_se, b_se, W_ih, b_ih, W_hh, W_kc, W_qc, W_vc, W_att, ws);
  k_gru<<<BN/4, 512, 0, stream>>>(x, W_init, b_init, b_hh, ws);
  k_kqv<<<Bb*Tt, 256, 0, stream>>>(ws);
  k_attn<<<Bb*Hh*4, 256, 0, stream>>>(ws);
  k_decode<<<BN/4, 384, 0, stream>>>(x, W_hh, b_hh, W_val, b_val, ws);
  k_final<<<Bb*4, 256, 0, stream>>>(W_dec, b_dec, W_mu, b_mu, W_sig, b_sig, b_att, ws, out);
}